// Round 7
// baseline (207.274 us; speedup 1.0000x reference)
//
#include <hip/hip_runtime.h>
#include <cstddef>

typedef _Float16 f16;
typedef _Float16 f16x8 __attribute__((ext_vector_type(8)));
typedef float f32x16 __attribute__((ext_vector_type(16)));

#define N_ 4
#define D_ 16
#define H_ 128
#define W_ 128
#define K_ 24
#define L_ 6
#define NTAP_A 13

// workspace byte offsets
#define OFF_TGT  0ull          // i32 [n][d][h][w]           (4 MB)
#define OFF_H0   4194304ull    // f16 [n][d][h][w][24]       (48 MB)
#define OFF_H1   54525952ull   // f16 [n][d][h][w][24]       (48 MB)
#define OFF_W0P  104857600ull  // f32 [13][24]
#define OFF_W1B  104858880ull  // f16 fragments, 10752 halves
#define OFF_W2B  104880384ull

// LDS geometry (bytes) for MFMA convs. A-tile: 19 rows (plane d-1: rows
// h-1..h+8 -> r0..9, plane d: rows h-1..h+7 -> r10..18), 132 slots * 48B.
#define AROW_B 6336
#define A_BYTES 120384         // 19 * 6336
#define B_BYTES 21504          // 21 chunks * 1024B
#define SMEM_BYTES 141888

// A-tile byte offset for chunk (p,c), lane-half g (output-row hs*6336 added
// at runtime). Chunk covers taps 2p,2p+1 (mask-B raster), 8-ci blocks.
__host__ __device__ constexpr int aoff(int p, int c, int g) {
  int idx8 = 2 * c + g;
  int ts = idx8 >= 3 ? 1 : 0;
  int t = 2 * p + ts;            // raster tap 0..13
  int cb = idx8 - 3 * ts;        // ci block of 8
  int dz = t / 9 - 1;
  int rr = t % 9;
  int dy = rr / 3 - 1;
  int dx = rr % 3 - 1;
  int rowb = (dz < 0) ? (dy + 1) : (10 + dy + 1);
  return rowb * AROW_B + (dx + 1) * 48 + cb * 16;
}

// ---------------------------------------------------------------- quantize helper
__device__ __forceinline__ void quant1(float xv, const float cs[L_],
                                       float& qb, int& sym) {
  float dv[L_];
  float dmin = 3.4e38f;
  sym = 0;
#pragma unroll
  for (int l = 0; l < L_; ++l) {
    float df = xv - cs[l];
    float d = df * df;
    dv[l] = d;
    if (d < dmin) { dmin = d; sym = l; }
  }
  float e[L_];
  float s = 0.f;
#pragma unroll
  for (int l = 0; l < L_; ++l) {
    e[l] = expf(dmin - dv[l]);
    s += e[l];
  }
  float qsoft = 0.f;
#pragma unroll
  for (int l = 0; l < L_; ++l) qsoft += (e[l] / s) * cs[l];
  qb = qsoft + (cs[sym] - qsoft);
}

// ---------------------------------------------------------------- qbar (coalesced NHWC) + weight pack
__global__ __launch_bounds__(256) void qbar_pack_k(
    const float* __restrict__ x, const float* __restrict__ centers,
    float* __restrict__ qbar_out,
    const float* __restrict__ w0, const float* __restrict__ w1,
    const float* __restrict__ w2, float* __restrict__ w0p,
    f16* __restrict__ w1B, f16* __restrict__ w2B) {
  int idx = blockIdx.x * 256 + threadIdx.x;   // natural NHWC order

  float cs[L_];
#pragma unroll
  for (int l = 0; l < L_; ++l) cs[l] = centers[l];

  float qb; int sym;
  quant1(x[idx], cs, qb, sym);
  qbar_out[idx] = qb;

  if (blockIdx.x < 8) {   // weight packing piggyback
    int gid = blockIdx.x * 256 + threadIdx.x;
    for (int i = gid; i < NTAP_A * K_; i += 2048) {
      int co = i % K_;
      int t  = i / K_;
      w0p[t * K_ + co] = w0[co * 27 + t];
    }
    // B fragments: halves idx = chunk*512 + g*256 + n*8 + j
    for (int i = gid; i < 2 * 10752; i += 2048) {
      int sel = i / 10752;
      int idx2 = i % 10752;
      int chunk = idx2 / 512;
      int r = idx2 % 512;
      int g = r / 256;
      int nn = (r % 256) / 8;
      int j = r % 8;
      int p = chunk / 3, c = chunk % 3;
      int idx8 = 2 * c + g;
      int ts = idx8 >= 3 ? 1 : 0;
      int t = 2 * p + ts;
      int ci = (idx8 - 3 * ts) * 8 + j;
      const float* w = sel ? w2 : w1;
      float v = (nn < K_) ? w[(nn * K_ + ci) * 27 + t] : 0.f;
      (sel ? w2B : w1B)[idx2] = (f16)v;
    }
  }
}

// ---------------------------------------------------------------- fused quantize + conv0 + tgt
// Per block: 8 output rows of one d-plane. Quantize the 19-row q halo into
// LDS from x directly, run the 13-tap 1->24 conv in VALU, write h0 coalesced
// via LDS staging, and write the tgt tile (coalesced; the center region's
// symbols fall out of the quantize pass for free).
__global__ __launch_bounds__(256, 2) void conv0_fused_k(
    const float* __restrict__ x, const float* __restrict__ centers,
    const float* __restrict__ w0p, const float* __restrict__ b0,
    f16* __restrict__ h0, int* __restrict__ tgt) {
  __shared__ float qs[19 * 132];
  __shared__ f16 eo[1024 * K_];   // 48 KB

  int blk = blockIdx.x;  // 1024 = 16 hb * 16 d * 4 n
  int hb = blk & 15;
  int d = (blk >> 4) & 15;
  int n = blk >> 8;
  int h_base = hb * 8;

  float cs[L_];
#pragma unroll
  for (int l = 0; l < L_; ++l) cs[l] = centers[l];
  float pv = cs[0];

  // quantize the halo region (pad AFTER quantization semantics: OOB = pv raw)
  for (int i = threadIdx.x; i < 19 * 130; i += 256) {
    int r = i / 130, s = i % 130;   // s-1 = w
    int dd = (r < 10) ? d - 1 : d;
    int hh = h_base - 1 + ((r < 10) ? r : r - 10);
    int ww = s - 1;
    float qv = pv;
    int sym = 0;
    bool in = (dd >= 0) && ((unsigned)hh < (unsigned)H_) &&
              ((unsigned)ww < (unsigned)W_);
    if (in) {
      float xv = x[((n * H_ + hh) * W_ + ww) * D_ + dd];
      quant1(xv, cs, qv, sym);
    }
    qs[r * 132 + s] = qv;
    if (r >= 11 && (unsigned)ww < (unsigned)W_)   // rows h..h+7, plane d
      tgt[((n * D_ + d) * H_ + (h_base + r - 11)) * W_ + ww] = sym;
  }
  __syncthreads();

  float bia[K_];
#pragma unroll
  for (int co = 0; co < K_; ++co) bia[co] = b0[co];  // uniform -> s_load

#pragma unroll 1
  for (int k = 0; k < 4; ++k) {
    int p = threadIdx.x + 256 * k;   // 0..1023
    int rl = p >> 7;                 // local row
    int wl = p & 127;

    float acc[K_];
#pragma unroll
    for (int co = 0; co < K_; ++co) acc[co] = bia[co];

#pragma unroll
    for (int t = 0; t < NTAP_A; ++t) {
      int r, s;
      if (t < 9)       { r = rl + t / 3; s = wl + t % 3; }      // dz=-1
      else if (t < 12) { r = rl + 10;    s = wl + (t - 9); }    // dz=0,dy=-1
      else             { r = rl + 11;    s = wl; }              // dz=0,dy=0,dx=-1
      float xv = qs[r * 132 + s];
      const float* wr = w0p + t * K_;
#pragma unroll
      for (int co = 0; co < K_; ++co) acc[co] = fmaf(xv, wr[co], acc[co]);
    }

    union { f16 hv[K_]; uint4 u[3]; } u;
#pragma unroll
    for (int co = 0; co < K_; ++co) u.hv[co] = (f16)fmaxf(acc[co], 0.f);
    uint4* ep = (uint4*)(eo + p * K_);
    ep[0] = u.u[0]; ep[1] = u.u[1]; ep[2] = u.u[2];
  }
  __syncthreads();

  {
    uint4* g = (uint4*)(h0 + (size_t)((n * D_ + d) * H_ + h_base) * (W_ * K_));
    const uint4* s = (const uint4*)eo;
    for (int i = threadIdx.x; i < 3072; i += 256) g[i] = s[i];
  }
}

// ---------------------------------------------------------------- MFMA core: stage 19-row A + B, 2 M-tiles/wave
__device__ __forceinline__ void conv_core8(const f16* __restrict__ src,
                                           const f16* __restrict__ wB,
                                           char* smem, int n, int d, int h_base,
                                           f32x16& acc0, f32x16& acc1) {
  const int tid = threadIdx.x;
  // stage A: 19 rows * 384 uint4 of data
  for (int i = tid; i < 7296; i += 1024) {
    int r = i / 384, qq = i % 384;
    int dd = (r < 10) ? d - 1 : d;
    int hh = h_base - 1 + ((r < 10) ? r : r - 10);
    uint4 v = make_uint4(0, 0, 0, 0);
    if (dd >= 0 && (unsigned)hh < (unsigned)H_)
      v = ((const uint4*)(src + (size_t)((n * D_ + dd) * H_ + hh) * 3072))[qq];
    *(uint4*)(smem + r * AROW_B + 48 + qq * 16) = v;
  }
  // halo zero: slots w=-1 and w=128 per row
  if (tid < 114) {
    int r = tid / 6, k = tid % 6;
    int byte = r * AROW_B + (k < 3 ? k * 16 : 6192 + (k - 3) * 16);
    *(uint4*)(smem + byte) = make_uint4(0, 0, 0, 0);
  }
  // stage B (once per 8 output rows)
  {
    const uint4* g = (const uint4*)wB;
    uint4* s = (uint4*)(smem + A_BYTES);
    for (int i = tid; i < 1344; i += 1024) s[i] = g[i];
  }
  __syncthreads();

  const int lane = tid & 63;
  const int wv = tid >> 6;        // 0..15
  const int m = lane & 31;
  const int g01 = lane >> 5;

  const int hs = wv >> 1;
  const int wc0 = (wv & 1) * 64;
  const char* Ab0 = smem + hs * AROW_B + (wc0 + m) * 48;
  const char* Ab1 = Ab0 + 32 * 48;
  const char* Bb = smem + A_BYTES + g01 * 512 + m * 16;

#pragma unroll
  for (int r = 0; r < 16; ++r) { acc0[r] = 0.f; acc1[r] = 0.f; }

#pragma unroll
  for (int p = 0; p < 7; ++p) {
#pragma unroll
    for (int c = 0; c < 3; ++c) {
      const int C0 = aoff(p, c, 0);
      const int C1 = aoff(p, c, 1);
      int off = g01 ? C1 : C0;
      f16x8 b = *(const f16x8*)(Bb + (p * 3 + c) * 1024);
      f16x8 a0 = *(const f16x8*)(Ab0 + off);
      f16x8 a1 = *(const f16x8*)(Ab1 + off);
      acc0 = __builtin_amdgcn_mfma_f32_32x32x16_f16(a0, b, acc0, 0, 0, 0);
      acc1 = __builtin_amdgcn_mfma_f32_32x32x16_f16(a1, b, acc1, 0, 0, 0);
    }
  }
}

// ---------------------------------------------------------------- conv1 (h0 -> h1, relu)
__global__ __launch_bounds__(1024, 1) void conv1_mfma_k(
    const f16* __restrict__ src, const f16* __restrict__ wB,
    const float* __restrict__ bias, f16* __restrict__ dst) {
  __shared__ __align__(16) char smem[SMEM_BYTES];

  int blk = blockIdx.x;          // 1024 = 16 hb * 16 d * 4 n
  int hb = blk & 15;
  int d = (blk >> 4) & 15;
  int n = blk >> 8;
  int h_base = hb * 8;

  f32x16 acc0, acc1;
  conv_core8(src, wB, smem, n, d, h_base, acc0, acc1);

  const int lane = threadIdx.x & 63;
  const int wv = threadIdx.x >> 6;
  const int m = lane & 31;
  const int g01 = lane >> 5;

  __syncthreads();  // A dead; reuse as E
  f16* ldsE = (f16*)smem;
  if (m < K_) {
    float bv = bias[m];
#pragma unroll
    for (int tt = 0; tt < 2; ++tt) {
      const f32x16& A = tt ? acc1 : acc0;
#pragma unroll
      for (int r = 0; r < 16; ++r) {
        int mrow = (r & 3) + 8 * (r >> 2) + 4 * g01;
        int pos = (2 * wv + tt) * 32 + mrow;
        ldsE[pos * K_ + m] = (f16)fmaxf(A[r] + bv, 0.f);
      }
    }
  }
  __syncthreads();
  {
    uint4* g = (uint4*)(dst + (size_t)((n * D_ + d) * H_ + h_base) * 3072);
    const uint4* s = (const uint4*)smem;
    for (int i = threadIdx.x; i < 3072; i += 1024) g[i] = s[i];
  }
}

// ---------------------------------------------------------------- conv2 + residual + relu + logits + bitcost
__global__ __launch_bounds__(1024, 1) void conv2_mfma_k(
    const f16* __restrict__ h1, const f16* __restrict__ h0,
    const f16* __restrict__ wB, const float* __restrict__ bias,
    const float* __restrict__ w_out, const float* __restrict__ b_out,
    const int* __restrict__ tgt, float* __restrict__ bco) {
  __shared__ __align__(16) char smem[SMEM_BYTES];

  int blk = blockIdx.x;
  int hb = blk & 15;
  int d = (blk >> 4) & 15;
  int n = blk >> 8;
  int h_base = hb * 8;

  f32x16 acc0, acc1;
  conv_core8(h1, wB, smem, n, d, h_base, acc0, acc1);

  const int lane = threadIdx.x & 63;
  const int wv = threadIdx.x >> 6;
  const int m = lane & 31;
  const int g01 = lane >> 5;

  __syncthreads();  // A dead; reuse as f32 E, row stride 28
  float* Ef = (float*)smem;
  if (m < K_) {
    float bv = bias[m];
#pragma unroll
    for (int tt = 0; tt < 2; ++tt) {
      const f32x16& A = tt ? acc1 : acc0;
#pragma unroll
      for (int r = 0; r < 16; ++r) {
        int mrow = (r & 3) + 8 * (r >> 2) + 4 * g01;
        int pos = (2 * wv + tt) * 32 + mrow;
        Ef[pos * 28 + m] = A[r] + bv;
      }
    }
  }
  __syncthreads();

  {
    int pos = threadIdx.x;             // 0..1023
    int hh = h_base + (pos >> 7);
    int w = pos & 127;

    size_t gpos = (size_t)((n * D_ + d) * H_ + h_base) * W_ + pos;
    const f16x8* hp = (const f16x8*)(h0 + gpos * K_);
    f16x8 e0 = hp[0], e1 = hp[1], e2 = hp[2];

    const float* ef = Ef + pos * 28;
    float vals[K_];
#pragma unroll
    for (int k = 0; k < K_; ++k) {
      float h0v = (float)(k < 8 ? e0[k] : (k < 16 ? e1[k - 8] : e2[k - 16]));
      vals[k] = fmaxf(ef[k] + h0v, 0.f);
    }

    float lg[L_];
#pragma unroll
    for (int l = 0; l < L_; ++l) lg[l] = b_out[l];
#pragma unroll
    for (int k = 0; k < K_; ++k) {
      float rv = vals[k];
#pragma unroll
      for (int l = 0; l < L_; ++l) lg[l] = fmaf(rv, w_out[l * K_ + k], lg[l]);
    }
    float mm = lg[0];
#pragma unroll
    for (int l = 1; l < L_; ++l) mm = fmaxf(mm, lg[l]);
    float s = 0.f;
#pragma unroll
    for (int l = 0; l < L_; ++l) s += expf(lg[l] - mm);

    int t = tgt[gpos];
    float lt = lg[0];
#pragma unroll
    for (int l = 1; l < L_; ++l) lt = (t == l) ? lg[l] : lt;

    float lp = lt - mm - logf(s);
    bco[(size_t)((n * H_ + hh) * W_ + w) * D_ + d] = -lp / 0.69314718055994530942f;
  }
}

// ---------------------------------------------------------------- launch
extern "C" void kernel_launch(void* const* d_in, const int* in_sizes, int n_in,
                              void* d_out, int out_size, void* d_ws, size_t ws_size,
                              hipStream_t stream) {
  const float* x       = (const float*)d_in[0];
  const float* centers = (const float*)d_in[1];
  const float* w0      = (const float*)d_in[2];
  const float* b0      = (const float*)d_in[3];
  const float* w1      = (const float*)d_in[4];
  const float* b1      = (const float*)d_in[5];
  const float* w2      = (const float*)d_in[6];
  const float* b2      = (const float*)d_in[7];
  const float* w_out   = (const float*)d_in[8];
  const float* b_out   = (const float*)d_in[9];
  float* out = (float*)d_out;

  char* ws = (char*)d_ws;
  int*   tg   = (int*)(ws + OFF_TGT);
  f16*   h0f  = (f16*)(ws + OFF_H0);
  f16*   h1f  = (f16*)(ws + OFF_H1);
  float* w0p  = (float*)(ws + OFF_W0P);
  f16*   w1B  = (f16*)(ws + OFF_W1B);
  f16*   w2B  = (f16*)(ws + OFF_W2B);

  hipLaunchKernelGGL(qbar_pack_k, dim3(4096), dim3(256), 0, stream,
                     x, centers, out, w0, w1, w2, w0p, w1B, w2B);
  hipLaunchKernelGGL(conv0_fused_k, dim3(1024), dim3(256), 0, stream,
                     x, centers, w0p, b0, h0f, tg);
  hipLaunchKernelGGL(conv1_mfma_k, dim3(1024), dim3(1024), 0, stream,
                     h0f, w1B, b1, h1f);
  hipLaunchKernelGGL(conv2_mfma_k, dim3(1024), dim3(1024), 0, stream,
                     h1f, h0f, w2B, b2, w_out, b_out, tg, out + 1048576);
}

// Round 10
// 200.596 us; speedup vs baseline: 1.0333x; 1.0333x over previous
//
#include <hip/hip_runtime.h>
#include <cstddef>

typedef _Float16 f16;
typedef _Float16 f16x8 __attribute__((ext_vector_type(8)));
typedef float f32x16 __attribute__((ext_vector_type(16)));

#define N_ 4
#define D_ 16
#define H_ 128
#define W_ 128
#define K_ 24
#define L_ 6
#define NTAP_A 13

// workspace byte offsets
#define OFF_TGT  0ull           // i32 [n][d][h][w]            (4 MB)
#define OFF_Q16  4194304ull     // f16 [n][d][h][w]            (2 MB)
#define OFF_H0   6291456ull     // f16 [n][d][h][w][24]        (48 MB)
#define OFF_H1   56623104ull    // f16 [n][d][h][w][24]        (48 MB)
#define OFF_W0P  106954752ull   // f32 [13][24]
#define OFF_W1B  106956800ull   // f16 fragments, 10752 halves
#define OFF_W2B  106978304ull

// LDS geometry (bytes) for MFMA convs. A-tile: 19 rows (plane d-1: rows
// h-1..h+8 -> r0..9, plane d: rows h-1..h+7 -> r10..18), 132 slots * 48B.
#define AROW_B 6336
#define A_BYTES 120384         // 19 * 6336
#define B_BYTES 21504          // 21 chunks * 1024B
#define SMEM_BYTES 141888

// A-tile byte offset for chunk (p,c), lane-half g (output-row hs*6336 added
// at runtime). Chunk covers taps 2p,2p+1 (mask-B raster), 8-ci blocks.
__host__ __device__ constexpr int aoff(int p, int c, int g) {
  int idx8 = 2 * c + g;
  int ts = idx8 >= 3 ? 1 : 0;
  int t = 2 * p + ts;            // raster tap 0..13
  int cb = idx8 - 3 * ts;        // ci block of 8
  int dz = t / 9 - 1;
  int rr = t % 9;
  int dy = rr / 3 - 1;
  int dx = rr % 3 - 1;
  int rowb = (dz < 0) ? (dy + 1) : (10 + dy + 1);
  return rowb * AROW_B + (dx + 1) * 48 + cb * 16;
}

// ---------------------------------------------------------------- quantize helper
__device__ __forceinline__ void quant1(float xv, const float cs[L_],
                                       float& qb, int& sym) {
  float dv[L_];
  float dmin = 3.4e38f;
  sym = 0;
#pragma unroll
  for (int l = 0; l < L_; ++l) {
    float df = xv - cs[l];
    float d = df * df;
    dv[l] = d;
    if (d < dmin) { dmin = d; sym = l; }
  }
  float e[L_];
  float s = 0.f;
#pragma unroll
  for (int l = 0; l < L_; ++l) {
    e[l] = expf(dmin - dv[l]);
    s += e[l];
  }
  float qsoft = 0.f;
#pragma unroll
  for (int l = 0; l < L_; ++l) qsoft += (e[l] / s) * cs[l];
  qb = qsoft + (cs[sym] - qsoft);
}

// ---------------------------------------------------------------- quant_all:
// qbar fp32 (NHWC, coalesced) + q16/tgt transposed [n][d][h][w] via LDS
// + weight pack spread over first 86 blocks (1 element/thread, no straggler).
__global__ __launch_bounds__(256) void quant_all_k(
    const float* __restrict__ x, const float* __restrict__ centers,
    float* __restrict__ qbar_out, f16* __restrict__ q16,
    int* __restrict__ tgt,
    const float* __restrict__ w0, const float* __restrict__ w1,
    const float* __restrict__ w2, float* __restrict__ w0p,
    f16* __restrict__ w1B, f16* __restrict__ w2B) {
  __shared__ f16 q16s[2048];   // [c][w]
  __shared__ int syms[2048];

  int blk = blockIdx.x;   // 512 = 4 n * 128 h
  int n = blk >> 7;
  int h = blk & 127;
  int t = threadIdx.x;

  float cs[L_];
#pragma unroll
  for (int l = 0; l < L_; ++l) cs[l] = centers[l];

  const float4* x4 = (const float4*)x + (size_t)blk * 512;
  float4* o4 = (float4*)qbar_out + (size_t)blk * 512;

  int w = t >> 1;
  int c0 = (t & 1) * 8;
#pragma unroll
  for (int e = 0; e < 2; ++e) {
    float4 v = x4[2 * t + e];
    float4 o;
    float qb; int sym;
    quant1(v.x, cs, qb, sym); o.x = qb;
    q16s[(c0 + 4 * e + 0) * 128 + w] = (f16)qb; syms[(c0 + 4 * e + 0) * 128 + w] = sym;
    quant1(v.y, cs, qb, sym); o.y = qb;
    q16s[(c0 + 4 * e + 1) * 128 + w] = (f16)qb; syms[(c0 + 4 * e + 1) * 128 + w] = sym;
    quant1(v.z, cs, qb, sym); o.z = qb;
    q16s[(c0 + 4 * e + 2) * 128 + w] = (f16)qb; syms[(c0 + 4 * e + 2) * 128 + w] = sym;
    quant1(v.w, cs, qb, sym); o.w = qb;
    q16s[(c0 + 4 * e + 3) * 128 + w] = (f16)qb; syms[(c0 + 4 * e + 3) * 128 + w] = sym;
    o4[2 * t + e] = o;
  }
  __syncthreads();

  for (int i = t; i < 2048; i += 256) {
    int dd = i >> 7, ww = i & 127;
    size_t g = ((size_t)(n * D_ + dd) * H_ + h) * W_ + ww;
    q16[g] = q16s[i];
    tgt[g] = syms[i];
  }

  // ---- weight pack (blocks 0..85, one element per thread) ----
  int pid = blk * 256 + t;
  if (pid < NTAP_A * K_) {
    int co = pid % K_;
    int tt = pid / K_;
    w0p[tt * K_ + co] = w0[co * 27 + tt];
  } else if (pid < NTAP_A * K_ + 2 * 10752) {
    int i2 = pid - NTAP_A * K_;
    int sel = i2 / 10752;
    int idx2 = i2 % 10752;
    int chunk = idx2 / 512;
    int r = idx2 % 512;
    int g = r / 256;
    int nn = (r % 256) / 8;
    int j = r % 8;
    int p = chunk / 3, cc = chunk % 3;
    int idx8 = 2 * cc + g;
    int ts = idx8 >= 3 ? 1 : 0;
    int tp = 2 * p + ts;
    int ci = (idx8 - 3 * ts) * 8 + j;
    const float* wsrc = sel ? w2 : w1;
    float v = (nn < K_) ? wsrc[(nn * K_ + ci) * 27 + tp] : 0.f;
    (sel ? w2B : w1B)[idx2] = (f16)v;
  }
}

// ---------------------------------------------------------------- conv0: q16 -> h0 (1->24, 13 taps, pad=centers[0])
// 4-row blocks; tiny q halo in LDS; h0 written straight from registers.
__global__ __launch_bounds__(256) void conv0_q16_k(
    const f16* __restrict__ q16, const float* __restrict__ centers,
    const float* __restrict__ w0p, const float* __restrict__ b0,
    f16* __restrict__ h0) {
  __shared__ f16 qs[2 * 6 * 132];   // [pl][rr][slot] = 3168 B

  int blk = blockIdx.x;   // 2048 = 32 hb * 16 d * 4 n
  int hb = blk & 31;
  int d = (blk >> 5) & 15;
  int n = blk >> 9;
  int h_base = hb * 4;

  f16 pv16 = (f16)centers[0];

  for (int i = threadIdx.x; i < 1584; i += 256) {
    int pl = i / 792;
    int rr = (i / 132) % 6;
    int s = i % 132;
    int qp = d - 1 + pl;
    int hh = h_base - 1 + rr;
    int ww = s - 1;
    f16 val = pv16;
    if (qp >= 0 && (unsigned)hh < (unsigned)H_ && (unsigned)ww < (unsigned)W_)
      val = q16[((size_t)(n * D_ + qp) * H_ + hh) * W_ + ww];
    qs[i] = val;
  }
  __syncthreads();

  float bia[K_];
#pragma unroll
  for (int co = 0; co < K_; ++co) bia[co] = b0[co];  // uniform -> s_load

#pragma unroll
  for (int k2 = 0; k2 < 2; ++k2) {
    int pos = threadIdx.x + 256 * k2;   // 0..511
    int rl = pos >> 7;
    int w = pos & 127;

    float acc[K_];
#pragma unroll
    for (int co = 0; co < K_; ++co) acc[co] = bia[co];

#pragma unroll
    for (int t = 0; t < NTAP_A; ++t) {
      int dz, dy, dx;
      if (t < 9)       { dz = -1; dy = t / 3 - 1; dx = t % 3 - 1; }
      else if (t < 12) { dz = 0;  dy = -1;        dx = t - 10; }
      else             { dz = 0;  dy = 0;         dx = -1; }
      float qv = (float)qs[(dz + 1) * 792 + (rl + dy + 1) * 132 + (w + dx + 1)];
      const float* wr = w0p + t * K_;
#pragma unroll
      for (int co = 0; co < K_; ++co) acc[co] = fmaf(qv, wr[co], acc[co]);
    }

    union { f16 hv[K_]; uint4 u[3]; } u;
#pragma unroll
    for (int co = 0; co < K_; ++co) u.hv[co] = (f16)fmaxf(acc[co], 0.f);
    uint4* dst = (uint4*)(h0 + ((size_t)((n * D_ + d) * H_ + h_base + rl) * W_ + w) * K_);
    dst[0] = u.u[0]; dst[1] = u.u[1]; dst[2] = u.u[2];
  }
}

// ---------------------------------------------------------------- MFMA core: stage 19-row A + B, 2 M-tiles/wave
__device__ __forceinline__ void conv_core8(const f16* __restrict__ src,
                                           const f16* __restrict__ wB,
                                           char* smem, int n, int d, int h_base,
                                           f32x16& acc0, f32x16& acc1) {
  const int tid = threadIdx.x;
  // stage A: 19 rows * 384 uint4 of data
  for (int i = tid; i < 7296; i += 1024) {
    int r = i / 384, qq = i % 384;
    int dd = (r < 10) ? d - 1 : d;
    int hh = h_base - 1 + ((r < 10) ? r : r - 10);
    uint4 v = make_uint4(0, 0, 0, 0);
    if (dd >= 0 && (unsigned)hh < (unsigned)H_)
      v = ((const uint4*)(src + (size_t)((n * D_ + dd) * H_ + hh) * 3072))[qq];
    *(uint4*)(smem + r * AROW_B + 48 + qq * 16) = v;
  }
  // halo zero: slots w=-1 and w=128 per row
  if (tid < 114) {
    int r = tid / 6, k = tid % 6;
    int byte = r * AROW_B + (k < 3 ? k * 16 : 6192 + (k - 3) * 16);
    *(uint4*)(smem + byte) = make_uint4(0, 0, 0, 0);
  }
  // stage B (once per 8 output rows)
  {
    const uint4* g = (const uint4*)wB;
    uint4* s = (uint4*)(smem + A_BYTES);
    for (int i = tid; i < 1344; i += 1024) s[i] = g[i];
  }
  __syncthreads();

  const int lane = tid & 63;
  const int wv = tid >> 6;        // 0..15
  const int m = lane & 31;
  const int g01 = lane >> 5;

  const int hs = wv >> 1;
  const int wc0 = (wv & 1) * 64;
  const char* Ab0 = smem + hs * AROW_B + (wc0 + m) * 48;
  const char* Ab1 = Ab0 + 32 * 48;
  const char* Bb = smem + A_BYTES + g01 * 512 + m * 16;

#pragma unroll
  for (int r = 0; r < 16; ++r) { acc0[r] = 0.f; acc1[r] = 0.f; }

#pragma unroll
  for (int p = 0; p < 7; ++p) {
#pragma unroll
    for (int c = 0; c < 3; ++c) {
      const int C0 = aoff(p, c, 0);
      const int C1 = aoff(p, c, 1);
      int off = g01 ? C1 : C0;
      f16x8 b = *(const f16x8*)(Bb + (p * 3 + c) * 1024);
      f16x8 a0 = *(const f16x8*)(Ab0 + off);
      f16x8 a1 = *(const f16x8*)(Ab1 + off);
      acc0 = __builtin_amdgcn_mfma_f32_32x32x16_f16(a0, b, acc0, 0, 0, 0);
      acc1 = __builtin_amdgcn_mfma_f32_32x32x16_f16(a1, b, acc1, 0, 0, 0);
    }
  }
}

// ---------------------------------------------------------------- conv1 (h0 -> h1, relu)
__global__ __launch_bounds__(1024, 1) void conv1_mfma_k(
    const f16* __restrict__ src, const f16* __restrict__ wB,
    const float* __restrict__ bias, f16* __restrict__ dst) {
  __shared__ __align__(16) char smem[SMEM_BYTES];

  int blk = blockIdx.x;          // 1024 = 16 hb * 16 d * 4 n
  int hb = blk & 15;
  int d = (blk >> 4) & 15;
  int n = blk >> 8;
  int h_base = hb * 8;

  f32x16 acc0, acc1;
  conv_core8(src, wB, smem, n, d, h_base, acc0, acc1);

  const int lane = threadIdx.x & 63;
  const int wv = threadIdx.x >> 6;
  const int m = lane & 31;
  const int g01 = lane >> 5;

  __syncthreads();  // A dead; reuse as E
  f16* ldsE = (f16*)smem;
  if (m < K_) {
    float bv = bias[m];
#pragma unroll
    for (int tt = 0; tt < 2; ++tt) {
      const f32x16& A = tt ? acc1 : acc0;
#pragma unroll
      for (int r = 0; r < 16; ++r) {
        int mrow = (r & 3) + 8 * (r >> 2) + 4 * g01;
        int pos = (2 * wv + tt) * 32 + mrow;
        ldsE[pos * K_ + m] = (f16)fmaxf(A[r] + bv, 0.f);
      }
    }
  }
  __syncthreads();
  {
    uint4* g = (uint4*)(dst + (size_t)((n * D_ + d) * H_ + h_base) * 3072);
    const uint4* s = (const uint4*)smem;
    for (int i = threadIdx.x; i < 3072; i += 1024) g[i] = s[i];
  }
}

// ---------------------------------------------------------------- conv2 + residual + relu + logits + bitcost
__global__ __launch_bounds__(1024, 1) void conv2_mfma_k(
    const f16* __restrict__ h1, const f16* __restrict__ h0,
    const f16* __restrict__ wB, const float* __restrict__ bias,
    const float* __restrict__ w_out, const float* __restrict__ b_out,
    const int* __restrict__ tgt, float* __restrict__ bco) {
  __shared__ __align__(16) char smem[SMEM_BYTES];

  int blk = blockIdx.x;
  int hb = blk & 15;
  int d = (blk >> 4) & 15;
  int n = blk >> 8;
  int h_base = hb * 8;

  f32x16 acc0, acc1;
  conv_core8(h1, wB, smem, n, d, h_base, acc0, acc1);

  const int lane = threadIdx.x & 63;
  const int wv = threadIdx.x >> 6;
  const int m = lane & 31;
  const int g01 = lane >> 5;

  __syncthreads();  // A dead; reuse as f32 E, row stride 28
  float* Ef = (float*)smem;
  if (m < K_) {
    float bv = bias[m];
#pragma unroll
    for (int tt = 0; tt < 2; ++tt) {
      const f32x16& A = tt ? acc1 : acc0;
#pragma unroll
      for (int r = 0; r < 16; ++r) {
        int mrow = (r & 3) + 8 * (r >> 2) + 4 * g01;
        int pos = (2 * wv + tt) * 32 + mrow;
        Ef[pos * 28 + m] = A[r] + bv;
      }
    }
  }
  __syncthreads();

  {
    int pos = threadIdx.x;             // 0..1023
    int hh = h_base + (pos >> 7);
    int w = pos & 127;

    size_t gpos = (size_t)((n * D_ + d) * H_ + h_base) * W_ + pos;
    const f16x8* hp = (const f16x8*)(h0 + gpos * K_);
    f16x8 e0 = hp[0], e1 = hp[1], e2 = hp[2];

    const float* ef = Ef + pos * 28;
    float vals[K_];
#pragma unroll
    for (int k = 0; k < K_; ++k) {
      float h0v = (float)(k < 8 ? e0[k] : (k < 16 ? e1[k - 8] : e2[k - 16]));
      vals[k] = fmaxf(ef[k] + h0v, 0.f);
    }

    float lg[L_];
#pragma unroll
    for (int l = 0; l < L_; ++l) lg[l] = b_out[l];
#pragma unroll
    for (int k = 0; k < K_; ++k) {
      float rv = vals[k];
#pragma unroll
      for (int l = 0; l < L_; ++l) lg[l] = fmaf(rv, w_out[l * K_ + k], lg[l]);
    }
    float mm = lg[0];
#pragma unroll
    for (int l = 1; l < L_; ++l) mm = fmaxf(mm, lg[l]);
    float s = 0.f;
#pragma unroll
    for (int l = 0; l < L_; ++l) s += expf(lg[l] - mm);

    int t = tgt[gpos];
    float lt = lg[0];
#pragma unroll
    for (int l = 1; l < L_; ++l) lt = (t == l) ? lg[l] : lt;

    float lp = lt - mm - logf(s);
    bco[(size_t)((n * H_ + hh) * W_ + w) * D_ + d] = -lp / 0.69314718055994530942f;
  }
}

// ---------------------------------------------------------------- launch
extern "C" void kernel_launch(void* const* d_in, const int* in_sizes, int n_in,
                              void* d_out, int out_size, void* d_ws, size_t ws_size,
                              hipStream_t stream) {
  const float* x       = (const float*)d_in[0];
  const float* centers = (const float*)d_in[1];
  const float* w0      = (const float*)d_in[2];
  const float* b0      = (const float*)d_in[3];
  const float* w1      = (const float*)d_in[4];
  const float* b1      = (const float*)d_in[5];
  const float* w2      = (const float*)d_in[6];
  const float* b2      = (const float*)d_in[7];
  const float* w_out   = (const float*)d_in[8];
  const float* b_out   = (const float*)d_in[9];
  float* out = (float*)d_out;

  char* ws = (char*)d_ws;
  int*   tg   = (int*)(ws + OFF_TGT);
  f16*   q16  = (f16*)(ws + OFF_Q16);
  f16*   h0f  = (f16*)(ws + OFF_H0);
  f16*   h1f  = (f16*)(ws + OFF_H1);
  float* w0p  = (float*)(ws + OFF_W0P);
  f16*   w1B  = (f16*)(ws + OFF_W1B);
  f16*   w2B  = (f16*)(ws + OFF_W2B);

  hipLaunchKernelGGL(quant_all_k, dim3(512), dim3(256), 0, stream,
                     x, centers, out, q16, tg, w0, w1, w2, w0p, w1B, w2B);
  hipLaunchKernelGGL(conv0_q16_k, dim3(2048), dim3(256), 0, stream,
                     q16, centers, w0p, b0, h0f);
  hipLaunchKernelGGL(conv1_mfma_k, dim3(1024), dim3(1024), 0, stream,
                     h0f, w1B, b1, h1f);
  hipLaunchKernelGGL(conv2_mfma_k, dim3(1024), dim3(1024), 0, stream,
                     h1f, h0f, w2B, b2, w_out, b_out, tg, out + 1048576);
}